// Round 2
// baseline (427.473 us; speedup 1.0000x reference)
//
#include <hip/hip_runtime.h>
#include <hip/hip_bf16.h>

// B=4, L=4096, D=1024, H=16, M=4, dk=64, n=1024. All-bf16 MFMA pipeline.
// R9: fix the R8 8-phase GEMM. Same geometry (256x256, BK=64, 8 waves 2x4,
// 128KB LDS dbuf, 16 MFMA/phase, counted vmcnt once per K-tile), but the
// steady loop is now BRANCH-FREE (u=0..13 unconditional stages; u=14 peeled
// with A-only stages + vmcnt(0); u=15 barrier-free drain) and each phase has
// the template's explicit s_waitcnt lgkmcnt(0) after the barrier. R8's
// in-phase conditionals created CFG merges -> conservative waitcnt drains ->
// 27% MfmaUtil. attn/cvt/vtrans unchanged.

typedef __attribute__((ext_vector_type(8))) short short8;
typedef __attribute__((ext_vector_type(8))) unsigned short ushort8v;
typedef __attribute__((ext_vector_type(4))) float floatx4;

__device__ __forceinline__ float b2f(unsigned short h) {
    union { unsigned int u; float f; } v; v.u = ((unsigned int)h) << 16; return v.f;
}
__device__ __forceinline__ unsigned short f2b(float f) {
    union { float f; unsigned int u; } v; v.f = f;
    unsigned int r = v.u + 0x7fffu + ((v.u >> 16) & 1u);
    return (unsigned short)(r >> 16);
}
__device__ __forceinline__ unsigned int fbits(float f) {
    union { float f; unsigned int u; } v; v.f = f; return v.u;
}
__device__ __forceinline__ void async_copy16(const unsigned short* g, unsigned short* l) {
    __builtin_amdgcn_global_load_lds((const __attribute__((address_space(1))) void*)g,
                                     (__attribute__((address_space(3))) void*)l, 16, 0, 0);
}

// ---------------- fp32 -> bf16 convert (x) ----------------
__global__ __launch_bounds__(256)
void cvt_kernel(const float* __restrict__ in, unsigned short* __restrict__ out, int n4) {
    int i = blockIdx.x * 256 + threadIdx.x;
    if (i >= n4) return;
    float4 v = ((const float4*)in)[i];
    ushort4 o;
    o.x = f2b(v.x); o.y = f2b(v.y); o.z = f2b(v.z); o.w = f2b(v.w);
    ((ushort4*)out)[i] = o;
}

// ---------------- W [K][N] fp32 -> Wt [N][K] bf16, all 4 weights in one grid ----------------
__global__ __launch_bounds__(256)
void cvt_w_t(const float* __restrict__ Wq, const float* __restrict__ Wk,
             const float* __restrict__ Wv, const float* __restrict__ Wo,
             unsigned short* __restrict__ Wt3, unsigned short* __restrict__ Wot, float s0) {
    __shared__ float tile[64][65];
    const int kt = blockIdx.x, nt = blockIdx.y, z = blockIdx.z;
    const float* W = (z == 0) ? Wq : (z == 1) ? Wk : (z == 2) ? Wv : Wo;
    unsigned short* Wt = (z < 3) ? (Wt3 + (size_t)z * 1048576) : Wot;
    const float sc = (z == 0) ? s0 : 1.0f;
    const int t = threadIdx.x;
    const int r = t >> 2, cg = t & 3;
    const float* src = W + (size_t)(kt * 64 + r) * 1024 + nt * 64 + cg * 16;
#pragma unroll
    for (int j = 0; j < 4; j++) {
        float4 v = *(const float4*)(src + j * 4);
        tile[r][cg * 16 + j * 4 + 0] = v.x;
        tile[r][cg * 16 + j * 4 + 1] = v.y;
        tile[r][cg * 16 + j * 4 + 2] = v.z;
        tile[r][cg * 16 + j * 4 + 3] = v.w;
    }
    __syncthreads();
    unsigned short* dst = Wt + (size_t)(nt * 64 + r) * 1024 + kt * 64 + cg * 16;
    ushort8v o0, o1;
#pragma unroll
    for (int j = 0; j < 8; j++) o0[j] = f2b(tile[cg * 16 + j][r] * sc);
#pragma unroll
    for (int j = 0; j < 8; j++) o1[j] = f2b(tile[cg * 16 + 8 + j][r] * sc);
    *(ushort8v*)(dst) = o0;
    *(ushort8v*)(dst + 8) = o1;
}

// ---------------- GEMM: C[M][N] = A[M][K] * Bt[N][K]^T + bias*bs ----------------
// BM=256, BN=256, BK=64; 512 threads = 8 waves (wr=w>>2 in {0,1}, wc=w&3).
// Per wave: 128x64 output = acc[8][4]; per K-tile 64 MFMA in 4 phases of 16;
// B-frags (8 ds_read_b128) preloaded once per tile before phase 0.
// Stage stream (race-free, barrier-separated):
//   tile u p0/p1: A(u+1) halves -> As[buf^1]
//   tile u p2/p3: B(u+2) halves -> Bs[buf]   (Bs[buf] read-complete at p0 MFMA)
// vmcnt(4) at p3 tail: B(u+2)'s 4 loads stay in flight across the tile
// boundary; everything older has landed. Peel: u=14 stages A(15) only and
// drains vmcnt(0); u=15 computes barrier-free.
#define GEMM_PHASE(RT0, RT1, STAGE_STMT, TAIL_STMT)                                                           \
    {                                                                                                         \
        short8 a0k0 = *(const short8*)(Ab + (RT0) * 1024 + kx0);                                              \
        short8 a0k1 = *(const short8*)(Ab + (RT0) * 1024 + kx1);                                              \
        short8 a1k0 = *(const short8*)(Ab + (RT1) * 1024 + kx0);                                              \
        short8 a1k1 = *(const short8*)(Ab + (RT1) * 1024 + kx1);                                              \
        STAGE_STMT                                                                                            \
        __builtin_amdgcn_s_barrier();                                                                         \
        asm volatile("s_waitcnt lgkmcnt(0)");                                                                 \
        __builtin_amdgcn_s_setprio(1);                                                                        \
        _Pragma("unroll") for (int ct = 0; ct < 4; ct++)                                                      \
            acc[RT0][ct] = __builtin_amdgcn_mfma_f32_16x16x32_bf16(a0k0, bfr[ct][0], acc[RT0][ct], 0, 0, 0);  \
        _Pragma("unroll") for (int ct = 0; ct < 4; ct++)                                                      \
            acc[RT1][ct] = __builtin_amdgcn_mfma_f32_16x16x32_bf16(a1k0, bfr[ct][0], acc[RT1][ct], 0, 0, 0);  \
        _Pragma("unroll") for (int ct = 0; ct < 4; ct++)                                                      \
            acc[RT0][ct] = __builtin_amdgcn_mfma_f32_16x16x32_bf16(a0k1, bfr[ct][1], acc[RT0][ct], 0, 0, 0);  \
        _Pragma("unroll") for (int ct = 0; ct < 4; ct++)                                                      \
            acc[RT1][ct] = __builtin_amdgcn_mfma_f32_16x16x32_bf16(a1k1, bfr[ct][1], acc[RT1][ct], 0, 0, 0);  \
        __builtin_amdgcn_s_setprio(0);                                                                        \
        TAIL_STMT                                                                                             \
        __builtin_amdgcn_s_barrier();                                                                         \
    }

#define BFR_PRELOAD                                                                                           \
    short8 bfr[4][2];                                                                                         \
    _Pragma("unroll") for (int ct = 0; ct < 4; ct++) {                                                        \
        bfr[ct][0] = *(const short8*)(Bb + ct * 1024 + kx0);                                                  \
        bfr[ct][1] = *(const short8*)(Bb + ct * 1024 + kx1);                                                  \
    }

template <bool F32OUT>
__global__ __launch_bounds__(512, 2)
void gemm_k(const unsigned short* __restrict__ A,
            const unsigned short* __restrict__ BtBase,
            const float* __restrict__ bias0,
            const float* __restrict__ bias1,
            const float* __restrict__ bias2,
            void* __restrict__ OutBase, float s0) {
    constexpr int K = 1024, N = 1024;
    __shared__ __align__(16) unsigned short As[2][16384];
    __shared__ __align__(16) unsigned short Bs[2][16384];
    const int id = blockIdx.x;
    const int xcd = id & 7;
    const int q = id >> 3;
    const int tileM = xcd * 8 + (q & 7);
    const int rz = q >> 3;
    const int tileN = rz & 3;
    const int z = rz >> 2;
    const unsigned short* Bt = BtBase + (size_t)z * (1024 * 1024);
    const float* bias = (z == 0) ? bias0 : (z == 1 ? bias1 : bias2);
    const float bs = (z == 0) ? s0 : 1.0f;
    const int tid = threadIdx.x, w = tid >> 6, lane = tid & 63;
    const int wr = w >> 2, wc = w & 3;
    const int g = lane >> 4, c = lane & 15;
    const int c7 = c & 7;
    const int r8 = lane >> 3, j8 = lane & 7;
    const int kcs = (j8 ^ r8) * 8;           // swizzled k-chunk this lane stages
    const int kx0 = ((g + 0) ^ c7) * 8;      // ds_read k-chunk, ks=0
    const int kx1 = ((g + 4) ^ c7) * 8;      // ds_read k-chunk, ks=1

    // wave w stages segments {h*16 + w*2, h*16 + w*2 + 1} of each 256-row tile
    const unsigned short* aBase = A  + (size_t)(tileM * 256 + w * 16 + r8) * K + kcs;
    const unsigned short* bBase = Bt + (size_t)(tileN * 256 + w * 16 + r8) * K + kcs;

    auto stageA = [&](int kt, int h, int nb) {
        async_copy16(aBase + (size_t)(h * 128) * K + kt * 64,     &As[nb][(h * 16 + w * 2 + 0) * 512]);
        async_copy16(aBase + (size_t)(h * 128 + 8) * K + kt * 64, &As[nb][(h * 16 + w * 2 + 1) * 512]);
    };
    auto stageB = [&](int kt, int h, int nb) {
        async_copy16(bBase + (size_t)(h * 128) * K + kt * 64,     &Bs[nb][(h * 16 + w * 2 + 0) * 512]);
        async_copy16(bBase + (size_t)(h * 128 + 8) * K + kt * 64, &Bs[nb][(h * 16 + w * 2 + 1) * 512]);
    };

    floatx4 acc[8][4];
#pragma unroll
    for (int i = 0; i < 8; i++)
#pragma unroll
        for (int jj = 0; jj < 4; jj++) acc[i][jj] = (floatx4){0.f, 0.f, 0.f, 0.f};

    // prologue: A(0), B(0), B(1) = 12 loads; keep B(1)'s 4 in flight
    stageA(0, 0, 0); stageA(0, 1, 0);
    stageB(0, 0, 0); stageB(0, 1, 0);
    stageB(1, 0, 1); stageB(1, 1, 1);
    asm volatile("s_waitcnt vmcnt(4)" ::: "memory");
    __builtin_amdgcn_s_barrier();

    // steady state: branch-free, unconditional stages
    for (int u = 0; u < 14; ++u) {
        const int buf = u & 1;
        const unsigned short* Ab = &As[buf][(wr * 128 + c) * 64];
        const unsigned short* Bb = &Bs[buf][(wc * 64 + c) * 64];
        BFR_PRELOAD
        GEMM_PHASE(0, 1, stageA(u + 1, 0, buf ^ 1);, ;)
        GEMM_PHASE(2, 3, stageA(u + 1, 1, buf ^ 1);, ;)
        GEMM_PHASE(4, 5, stageB(u + 2, 0, buf);, ;)
        GEMM_PHASE(6, 7, stageB(u + 2, 1, buf);,
                   asm volatile("s_waitcnt vmcnt(4)" ::: "memory");)
    }
    // u = 14 (buf 0): stage A(15) only, drain everything at the end
    {
        const unsigned short* Ab = &As[0][(wr * 128 + c) * 64];
        const unsigned short* Bb = &Bs[0][(wc * 64 + c) * 64];
        BFR_PRELOAD
        GEMM_PHASE(0, 1, stageA(15, 0, 1);, ;)
        GEMM_PHASE(2, 3, stageA(15, 1, 1);, ;)
        GEMM_PHASE(4, 5, ;, ;)
        GEMM_PHASE(6, 7, ;, asm volatile("s_waitcnt vmcnt(0)" ::: "memory");)
    }
    // u = 15 (buf 1): pure drain, no stages, no barriers
    {
        const unsigned short* Ab = &As[1][(wr * 128 + c) * 64];
        const unsigned short* Bb = &Bs[1][(wc * 64 + c) * 64];
        BFR_PRELOAD
#pragma unroll
        for (int rt = 0; rt < 8; rt++) {
            short8 ak0 = *(const short8*)(Ab + rt * 1024 + kx0);
            short8 ak1 = *(const short8*)(Ab + rt * 1024 + kx1);
#pragma unroll
            for (int ct = 0; ct < 4; ct++)
                acc[rt][ct] = __builtin_amdgcn_mfma_f32_16x16x32_bf16(ak0, bfr[ct][0], acc[rt][ct], 0, 0, 0);
#pragma unroll
            for (int ct = 0; ct < 4; ct++)
                acc[rt][ct] = __builtin_amdgcn_mfma_f32_16x16x32_bf16(ak1, bfr[ct][1], acc[rt][ct], 0, 0, 0);
        }
    }

#pragma unroll
    for (int ct = 0; ct < 4; ct++) {
        int col = tileN * 256 + wc * 64 + ct * 16 + c;
        float bvv = bias[col] * bs;
#pragma unroll
        for (int rt = 0; rt < 8; rt++) {
            int row0 = tileM * 256 + wr * 128 + rt * 16 + g * 4;
#pragma unroll
            for (int r = 0; r < 4; r++) {
                float v = acc[rt][ct][r] + bvv;
                if (F32OUT) {
                    ((float*)OutBase)[(size_t)(row0 + r) * N + col] = v;
                } else {
                    ((unsigned short*)OutBase)[(size_t)z * (16384ull * 1024ull) +
                                               (size_t)(row0 + r) * N + col] = f2b(v);
                }
            }
        }
    }
}

// ---------------- V transpose: v[B,L,D] -> Vt[slice=(b,h,m)][d=64][i=1024] ----------------
__global__ __launch_bounds__(256)
void vtrans(const unsigned short* __restrict__ V, unsigned short* __restrict__ Vt) {
    __shared__ unsigned short tile[64 * 72];
    const int it = blockIdx.x, s = blockIdx.y;
    const int m = s & 3, h = (s >> 2) & 15, b = s >> 6;
    const int tid = threadIdx.x;
    {
        int il = tid >> 2, cg = tid & 3;
        const unsigned short* gsrc =
            V + ((size_t)b * 4096 + m + 4 * (it * 64 + il)) * 1024 + h * 64 + cg * 16;
        *(ushort8v*)(tile + il * 72 + cg * 16) = *(const ushort8v*)gsrc;
        *(ushort8v*)(tile + il * 72 + cg * 16 + 8) = *(const ushort8v*)(gsrc + 8);
    }
    __syncthreads();
    {
        int dl = tid >> 2, ig = (tid & 3) * 16;
        ushort8v o0, o1;
#pragma unroll
        for (int j = 0; j < 8; j++) o0[j] = tile[(ig + j) * 72 + dl];
#pragma unroll
        for (int j = 0; j < 8; j++) o1[j] = tile[(ig + 8 + j) * 72 + dl];
        unsigned short* dst = Vt + (size_t)s * 65536 + (size_t)dl * 1024 + it * 64 + ig;
        *(ushort8v*)dst = o0;
        *(ushort8v*)(dst + 8) = o1;
    }
}

// ---------------- Attention ----------------
// 1-D grid 2048 blocks; decode xcd=id&7, q=id>>3, s=xcd*32+(q>>3), qt=q&7.
// Q frags live in registers (loaded once). S^T = K·Q^T; p=exp2(s) (scale folded
// into Wq); P packed to bf16 via v_perm_b32 into per-wave LDS; O = P·V with an
// extra all-ones B-frag MFMA accumulating l per-row in oacc-matched layout.
__global__ __launch_bounds__(256, 4)
void attn_k(const unsigned short* __restrict__ Qg,
            const unsigned short* __restrict__ Kg,
            const unsigned short* __restrict__ Vt,
            unsigned short* __restrict__ Og) {
    __shared__ __align__(16) unsigned short Ks[64 * 64];    // [kt4][ks][g][c][8]
    __shared__ __align__(16) unsigned short Vs[64 * 64];    // [dt][kc][g][c][8]
    __shared__ __align__(16) unsigned short Ps[4 * 2048];   // per-wave [rt*2+kc][g][c][8]

    const int id = blockIdx.x;
    const int xcd = id & 7;
    const int qq = id >> 3;
    const int s = xcd * 32 + (qq >> 3);
    const int qt = qq & 7;
    const int m = s & 3, h = (s >> 2) & 15, b = s >> 6;
    const int tid = threadIdx.x, w = tid >> 6, lane = tid & 63;
    const int g = lane >> 4, c = lane & 15;
    const size_t rowBase = (size_t)b * 4096;

    // Q fragments straight to registers (read-once data; 16B/lane)
    short8 qf[2][2];
#pragma unroll
    for (int rt = 0; rt < 2; rt++)
#pragma unroll
        for (int ks = 0; ks < 2; ks++)
            qf[rt][ks] = *(const short8*)(Qg +
                (rowBase + (size_t)(m + 4 * (qt * 128 + w * 32 + rt * 16 + c))) * 1024 +
                h * 64 + ks * 32 + g * 8);

    // strength-reduced staging pointers
    const unsigned short* kPtr =
        Kg + (rowBase + (size_t)(m + 4 * (w * 16 + c))) * 1024 + h * 64 + g * 8;
    const unsigned short* vPtr =
        Vt + (size_t)s * 65536 + (size_t)(w * 16 + c) * 1024 + g * 8;

    // all-ones B-fragment: l-column trick
    short8 ones;
#pragma unroll
    for (int j = 0; j < 8; j++) ones[j] = (short)0x3F80;   // bf16 1.0

    floatx4 oacc[2][4], lacc[2];
#pragma unroll
    for (int rt = 0; rt < 2; rt++) {
        lacc[rt] = (floatx4){0.f, 0.f, 0.f, 0.f};
#pragma unroll
        for (int dt = 0; dt < 4; dt++) oacc[rt][dt] = (floatx4){0.f, 0.f, 0.f, 0.f};
    }

    for (int kt = 0; kt < 16; ++kt) {
        __syncthreads();
        async_copy16(kPtr,      Ks + (w * 2 + 0) * 512);
        async_copy16(kPtr + 32, Ks + (w * 2 + 1) * 512);
        async_copy16(vPtr,      Vs + (w * 2 + 0) * 512);
        async_copy16(vPtr + 32, Vs + (w * 2 + 1) * 512);
        kPtr += 262144;   // 256 tokens * 1024 elems
        vPtr += 64;       // 64 keys along i-dim
        __syncthreads();

        // S^T[key][q] = K·Q^T : A=K (4 key-tiles), B=Q (2 q-tiles, regs)
        floatx4 sacc[4][2];
#pragma unroll
        for (int k4 = 0; k4 < 4; k4++)
#pragma unroll
            for (int rt = 0; rt < 2; rt++) sacc[k4][rt] = (floatx4){0.f, 0.f, 0.f, 0.f};
#pragma unroll
        for (int ks = 0; ks < 2; ks++) {
            short8 kf[4];
#pragma unroll
            for (int k4 = 0; k4 < 4; k4++)
                kf[k4] = *(const short8*)(Ks + (((k4 * 2 + ks) * 4 + g) * 16 + c) * 8);
#pragma unroll
            for (int k4 = 0; k4 < 4; k4++)
#pragma unroll
                for (int rt = 0; rt < 2; rt++)
                    sacc[k4][rt] = __builtin_amdgcn_mfma_f32_16x16x32_bf16(kf[k4], qf[rt][ks], sacc[k4][rt], 0, 0, 0);
        }

        // p = exp2(s), pack pairs via v_perm_b32, write b64 to per-wave Ps
#pragma unroll
        for (int k4 = 0; k4 < 4; k4++) {
            const int kc = k4 >> 1;
            const int gr = (k4 & 1) * 2 + (g >> 1);
            const int j0 = (g & 1) * 4;
#pragma unroll
            for (int rt = 0; rt < 2; rt++) {
                unsigned int u0 = fbits(__builtin_amdgcn_exp2f(sacc[k4][rt][0])) + 0x8000u;
                unsigned int u1 = fbits(__builtin_amdgcn_exp2f(sacc[k4][rt][1])) + 0x8000u;
                unsigned int u2 = fbits(__builtin_amdgcn_exp2f(sacc[k4][rt][2])) + 0x8000u;
                unsigned int u3 = fbits(__builtin_amdgcn_exp2f(sacc[k4][rt][3])) + 0x8000u;
                uint2 pk;
                pk.x = __builtin_amdgcn_perm(u1, u0, 0x07060302u);  // [e1.hi16 : e0.hi16]
                pk.y = __builtin_amdgcn_perm(u3, u2, 0x07060302u);
                *(uint2*)(Ps + w * 2048 + (((rt * 2 + kc) * 4 + gr) * 16 + c) * 8 + j0) = pk;
            }
        }

        // O += P·V ; l += P·1  (ones B-frag -> l lands oacc-aligned per row)
#pragma unroll
        for (int kc = 0; kc < 2; kc++) {
            short8 pf[2], vf[4];
#pragma unroll
            for (int rt = 0; rt < 2; rt++)
                pf[rt] = *(const short8*)(Ps + w * 2048 + (((rt * 2 + kc) * 4 + g) * 16 + c) * 8);
#pragma unroll
            for (int dt = 0; dt < 4; dt++)
                vf[dt] = *(const short8*)(Vs + (((dt * 2 + kc) * 4 + g) * 16 + c) * 8);
#pragma unroll
            for (int rt = 0; rt < 2; rt++) {
                lacc[rt] = __builtin_amdgcn_mfma_f32_16x16x32_bf16(pf[rt], ones, lacc[rt], 0, 0, 0);
#pragma unroll
                for (int dt = 0; dt < 4; dt++)
                    oacc[rt][dt] = __builtin_amdgcn_mfma_f32_16x16x32_bf16(pf[rt], vf[dt], oacc[rt][dt], 0, 0, 0);
            }
        }
    }

    // epilogue: l is already per-row in matching slots; normalize and scatter
#pragma unroll
    for (int rt = 0; rt < 2; rt++) {
#pragma unroll
        for (int r = 0; r < 4; r++) {
            float inv = 1.0f / lacc[rt][r];
            int token = m + 4 * (qt * 128 + w * 32 + rt * 16 + g * 4 + r);
            size_t rowOff = (rowBase + token) * 1024 + h * 64;
#pragma unroll
            for (int dt = 0; dt < 4; dt++)
                Og[rowOff + dt * 16 + c] = f2b(oacc[rt][dt][r] * inv);
        }
    }
}

extern "C" void kernel_launch(void* const* d_in, const int* in_sizes, int n_in,
                              void* d_out, int out_size, void* d_ws, size_t ws_size,
                              hipStream_t stream) {
    const float* x  = (const float*)d_in[0];
    const float* Wq = (const float*)d_in[1];
    const float* bq = (const float*)d_in[2];
    const float* Wk = (const float*)d_in[3];
    const float* bk = (const float*)d_in[4];
    const float* Wv = (const float*)d_in[5];
    const float* bv = (const float*)d_in[6];
    const float* Wo = (const float*)d_in[7];
    const float* bo = (const float*)d_in[8];

    const float SC = 0.18033688011112042f;  // (1/8) * log2(e), folded into Wq/bq

    char* ws = (char*)d_ws;
    const size_t SZ = 33554432;  // 32 MB = 16M bf16
    unsigned short* xb  = (unsigned short*)(ws);          // dead after QKV gemm
    unsigned short* Vtp = (unsigned short*)(ws);          // reuses xb region
    unsigned short* qb  = (unsigned short*)(ws + SZ);     // q,k,v contiguous
    unsigned short* ob  = (unsigned short*)(ws + 4 * SZ);
    unsigned short* Wt3 = (unsigned short*)(ws + 5 * SZ);
    unsigned short* Wot = Wt3 + 3ull * 1024 * 1024;

    cvt_kernel<<<16384, 256, 0, stream>>>(x, xb, 4194304);
    cvt_w_t<<<dim3(16, 16, 4), 256, 0, stream>>>(Wq, Wk, Wv, Wo, Wt3, Wot, SC);
    gemm_k<false><<<768, 512, 0, stream>>>(xb, Wt3, bq, bk, bv, qb, SC);
    vtrans<<<dim3(16, 256), 256, 0, stream>>>(qb + 2ull * 16777216ull, Vtp);
    attn_k<<<2048, 256, 0, stream>>>(qb, qb + 16777216ull, Vtp, ob);
    gemm_k<true><<<256, 512, 0, stream>>>(ob, Wot, bo, bo, bo, d_out, 1.0f);
}

// Round 6
// 394.617 us; speedup vs baseline: 1.0833x; 1.0833x over previous
//
#include <hip/hip_runtime.h>
#include <hip/hip_bf16.h>

// B=4, L=4096, D=1024, H=16, M=4, dk=64, n=1024. All-bf16 MFMA pipeline.
// R13 = R11 resubmitted verbatim (R11/R12 benches were infra failures:
// container failure, then GPU acquisition timeout — no measurements).
// attn_k keeps K/V double-buffer (prefetch kt+1 into buf^1 before computing
// kt) but per-tile sync is __syncthreads() — full vmcnt+lgkmcnt drain +
// barrier. R10's vmcnt-only + raw s_barrier raced: outstanding ds_reads of
// buf^1 could sample LDS after the next tile's global_load_lds writes landed
// (post-timing divergence). Also adds T5 s_setprio(1) around attn MFMA
// clusters (3 blocks/CU at independent phases — m191 regime, +4-7%).
// gemm_k stays the proven R7 structure (117us QKV).

typedef __attribute__((ext_vector_type(8))) short short8;
typedef __attribute__((ext_vector_type(8))) unsigned short ushort8v;
typedef __attribute__((ext_vector_type(4))) float floatx4;

__device__ __forceinline__ float b2f(unsigned short h) {
    union { unsigned int u; float f; } v; v.u = ((unsigned int)h) << 16; return v.f;
}
__device__ __forceinline__ unsigned short f2b(float f) {
    union { float f; unsigned int u; } v; v.f = f;
    unsigned int r = v.u + 0x7fffu + ((v.u >> 16) & 1u);
    return (unsigned short)(r >> 16);
}
__device__ __forceinline__ unsigned int fbits(float f) {
    union { float f; unsigned int u; } v; v.f = f; return v.u;
}
__device__ __forceinline__ void async_copy16(const unsigned short* g, unsigned short* l) {
    __builtin_amdgcn_global_load_lds((const __attribute__((address_space(1))) void*)g,
                                     (__attribute__((address_space(3))) void*)l, 16, 0, 0);
}

// ---------------- fp32 -> bf16 convert (x) ----------------
__global__ __launch_bounds__(256)
void cvt_kernel(const float* __restrict__ in, unsigned short* __restrict__ out, int n4) {
    int i = blockIdx.x * 256 + threadIdx.x;
    if (i >= n4) return;
    float4 v = ((const float4*)in)[i];
    ushort4 o;
    o.x = f2b(v.x); o.y = f2b(v.y); o.z = f2b(v.z); o.w = f2b(v.w);
    ((ushort4*)out)[i] = o;
}

// ---------------- W [K][N] fp32 -> Wt [N][K] bf16, all 4 weights in one grid ----------------
__global__ __launch_bounds__(256)
void cvt_w_t(const float* __restrict__ Wq, const float* __restrict__ Wk,
             const float* __restrict__ Wv, const float* __restrict__ Wo,
             unsigned short* __restrict__ Wt3, unsigned short* __restrict__ Wot, float s0) {
    __shared__ float tile[64][65];
    const int kt = blockIdx.x, nt = blockIdx.y, z = blockIdx.z;
    const float* W = (z == 0) ? Wq : (z == 1) ? Wk : (z == 2) ? Wv : Wo;
    unsigned short* Wt = (z < 3) ? (Wt3 + (size_t)z * 1048576) : Wot;
    const float sc = (z == 0) ? s0 : 1.0f;
    const int t = threadIdx.x;
    const int r = t >> 2, cg = t & 3;
    const float* src = W + (size_t)(kt * 64 + r) * 1024 + nt * 64 + cg * 16;
#pragma unroll
    for (int j = 0; j < 4; j++) {
        float4 v = *(const float4*)(src + j * 4);
        tile[r][cg * 16 + j * 4 + 0] = v.x;
        tile[r][cg * 16 + j * 4 + 1] = v.y;
        tile[r][cg * 16 + j * 4 + 2] = v.z;
        tile[r][cg * 16 + j * 4 + 3] = v.w;
    }
    __syncthreads();
    unsigned short* dst = Wt + (size_t)(nt * 64 + r) * 1024 + kt * 64 + cg * 16;
    ushort8v o0, o1;
#pragma unroll
    for (int j = 0; j < 8; j++) o0[j] = f2b(tile[cg * 16 + j][r] * sc);
#pragma unroll
    for (int j = 0; j < 8; j++) o1[j] = f2b(tile[cg * 16 + 8 + j][r] * sc);
    *(ushort8v*)(dst) = o0;
    *(ushort8v*)(dst + 8) = o1;
}

// ---------------- GEMM: C[M][N] = A[M][K] * Bt[N][K]^T + bias*bs ----------------
// BM=256, BN=128, BK=64; 4 waves (2x2), 8x4 accum/wave = 64 MFMA per K-iter.
// LDS XOR swizzle: chunk(row,kc) @ elem (row*8 + (kc^(row&7)))*8.
// Grid 512*nz: xcd=id&7, q=id>>3, tileM=xcd*8+(q&7), rz=q>>3, tileN=rz&7, z=rz>>3.
template <bool F32OUT>
__global__ __launch_bounds__(256, 2)
void gemm_k(const unsigned short* __restrict__ A,
            const unsigned short* __restrict__ BtBase,
            const float* __restrict__ bias0,
            const float* __restrict__ bias1,
            const float* __restrict__ bias2,
            void* __restrict__ OutBase, float s0) {
    constexpr int K = 1024, N = 1024;
    __shared__ __align__(16) unsigned short As[256 * 64];
    __shared__ __align__(16) unsigned short Bs[128 * 64];
    const int id = blockIdx.x;
    const int xcd = id & 7;
    const int q = id >> 3;
    const int tileM = xcd * 8 + (q & 7);
    const int rz = q >> 3;
    const int tileN = rz & 7;
    const int z = rz >> 3;
    const unsigned short* Bt = BtBase + (size_t)z * (1024 * 1024);
    const float* bias = (z == 0) ? bias0 : (z == 1 ? bias1 : bias2);
    const float bs = (z == 0) ? s0 : 1.0f;
    const int tid = threadIdx.x, w = tid >> 6, lane = tid & 63;
    const int wr = w >> 1, wc = w & 1;
    const int g = lane >> 4, c = lane & 15;
    const int c7 = c & 7;
    const int r8 = lane >> 3, j8 = lane & 7;
    const int kcs = (j8 ^ r8) * 8;   // swizzled k-chunk this lane stages

    floatx4 acc[8][4];
#pragma unroll
    for (int i = 0; i < 8; i++)
#pragma unroll
        for (int jj = 0; jj < 4; jj++) acc[i][jj] = (floatx4){0.f, 0.f, 0.f, 0.f};

    for (int kt = 0; kt < K / 64; ++kt) {
        __syncthreads();
#pragma unroll
        for (int t = 0; t < 8; t++) {          // A: 32 segs of 8 rows
            int seg = w * 8 + t;
            int rowA = tileM * 256 + seg * 8 + r8;
            async_copy16(A + (size_t)rowA * K + kt * 64 + kcs, As + seg * 512);
        }
#pragma unroll
        for (int t = 0; t < 4; t++) {          // B: 16 segs of 8 rows
            int seg = w * 4 + t;
            int rowB = tileN * 128 + seg * 8 + r8;
            async_copy16(Bt + (size_t)rowB * K + kt * 64 + kcs, Bs + seg * 512);
        }
        __syncthreads();
#pragma unroll
        for (int ks = 0; ks < 2; ks++) {
            const int kx = ((ks * 4 + g) ^ c7) * 8;
            short8 bf[4];
#pragma unroll
            for (int ct = 0; ct < 4; ct++)
                bf[ct] = *(const short8*)(Bs + (wc * 64 + ct * 16 + c) * 64 + kx);
#pragma unroll
            for (int rt = 0; rt < 8; rt++) {
                short8 af = *(const short8*)(As + (wr * 128 + rt * 16 + c) * 64 + kx);
#pragma unroll
                for (int ct = 0; ct < 4; ct++)
                    acc[rt][ct] = __builtin_amdgcn_mfma_f32_16x16x32_bf16(af, bf[ct], acc[rt][ct], 0, 0, 0);
            }
        }
    }
#pragma unroll
    for (int ct = 0; ct < 4; ct++) {
        int col = tileN * 128 + wc * 64 + ct * 16 + c;
        float bvv = bias[col] * bs;
#pragma unroll
        for (int rt = 0; rt < 8; rt++) {
            int row0 = tileM * 256 + wr * 128 + rt * 16 + g * 4;
#pragma unroll
            for (int r = 0; r < 4; r++) {
                float v = acc[rt][ct][r] + bvv;
                if (F32OUT) {
                    ((float*)OutBase)[(size_t)(row0 + r) * N + col] = v;
                } else {
                    ((unsigned short*)OutBase)[(size_t)z * (16384ull * 1024ull) +
                                               (size_t)(row0 + r) * N + col] = f2b(v);
                }
            }
        }
    }
}

// ---------------- V transpose: v[B,L,D] -> Vt[slice=(b,h,m)][d=64][i=1024] ----------------
__global__ __launch_bounds__(256)
void vtrans(const unsigned short* __restrict__ V, unsigned short* __restrict__ Vt) {
    __shared__ unsigned short tile[64 * 72];
    const int it = blockIdx.x, s = blockIdx.y;
    const int m = s & 3, h = (s >> 2) & 15, b = s >> 6;
    const int tid = threadIdx.x;
    {
        int il = tid >> 2, cg = tid & 3;
        const unsigned short* gsrc =
            V + ((size_t)b * 4096 + m + 4 * (it * 64 + il)) * 1024 + h * 64 + cg * 16;
        *(ushort8v*)(tile + il * 72 + cg * 16) = *(const ushort8v*)gsrc;
        *(ushort8v*)(tile + il * 72 + cg * 16 + 8) = *(const ushort8v*)(gsrc + 8);
    }
    __syncthreads();
    {
        int dl = tid >> 2, ig = (tid & 3) * 16;
        ushort8v o0, o1;
#pragma unroll
        for (int j = 0; j < 8; j++) o0[j] = tile[(ig + j) * 72 + dl];
#pragma unroll
        for (int j = 0; j < 8; j++) o1[j] = tile[(ig + 8 + j) * 72 + dl];
        unsigned short* dst = Vt + (size_t)s * 65536 + (size_t)dl * 1024 + it * 64 + ig;
        *(ushort8v*)dst = o0;
        *(ushort8v*)(dst + 8) = o1;
    }
}

// ---------------- Attention ----------------
// 1-D grid 2048 blocks; decode xcd=id&7, q=id>>3, s=xcd*32+(q>>3), qt=q&7.
// Q frags in registers. S^T = K·Q^T; p=exp2(s) (scale folded into Wq); P
// packed to bf16 via v_perm_b32 into per-wave LDS; O = P·V with all-ones
// B-frag MFMA accumulating l. K/V double-buffered: prefetch kt+1 into buf^1
// before computing kt; ONE __syncthreads per tile (full drain — race-safe).
// setprio(1) around MFMA clusters (T5; 3 blocks/CU at independent phases).
__global__ __launch_bounds__(256, 3)
void attn_k(const unsigned short* __restrict__ Qg,
            const unsigned short* __restrict__ Kg,
            const unsigned short* __restrict__ Vt,
            unsigned short* __restrict__ Og) {
    __shared__ __align__(16) unsigned short Ks[2][64 * 64];  // [buf][kt4][ks][g][c][8]
    __shared__ __align__(16) unsigned short Vs[2][64 * 64];  // [buf][dt][kc][g][c][8]
    __shared__ __align__(16) unsigned short Ps[4 * 2048];    // per-wave [rt*2+kc][g][c][8]

    const int id = blockIdx.x;
    const int xcd = id & 7;
    const int qq = id >> 3;
    const int s = xcd * 32 + (qq >> 3);
    const int qt = qq & 7;
    const int m = s & 3, h = (s >> 2) & 15, b = s >> 6;
    const int tid = threadIdx.x, w = tid >> 6, lane = tid & 63;
    const int g = lane >> 4, c = lane & 15;
    const size_t rowBase = (size_t)b * 4096;

    // Q fragments straight to registers (read-once data; 16B/lane)
    short8 qf[2][2];
#pragma unroll
    for (int rt = 0; rt < 2; rt++)
#pragma unroll
        for (int ks = 0; ks < 2; ks++)
            qf[rt][ks] = *(const short8*)(Qg +
                (rowBase + (size_t)(m + 4 * (qt * 128 + w * 32 + rt * 16 + c))) * 1024 +
                h * 64 + ks * 32 + g * 8);

    // strength-reduced staging pointers
    const unsigned short* kPtr =
        Kg + (rowBase + (size_t)(m + 4 * (w * 16 + c))) * 1024 + h * 64 + g * 8;
    const unsigned short* vPtr =
        Vt + (size_t)s * 65536 + (size_t)(w * 16 + c) * 1024 + g * 8;

    // all-ones B-fragment: l-column trick
    short8 ones;
#pragma unroll
    for (int j = 0; j < 8; j++) ones[j] = (short)0x3F80;   // bf16 1.0

    floatx4 oacc[2][4], lacc[2];
#pragma unroll
    for (int rt = 0; rt < 2; rt++) {
        lacc[rt] = (floatx4){0.f, 0.f, 0.f, 0.f};
#pragma unroll
        for (int dt = 0; dt < 4; dt++) oacc[rt][dt] = (floatx4){0.f, 0.f, 0.f, 0.f};
    }

    auto stage = [&](int nb) {
        async_copy16(kPtr,      &Ks[nb][(w * 2 + 0) * 512]);
        async_copy16(kPtr + 32, &Ks[nb][(w * 2 + 1) * 512]);
        async_copy16(vPtr,      &Vs[nb][(w * 2 + 0) * 512]);
        async_copy16(vPtr + 32, &Vs[nb][(w * 2 + 1) * 512]);
        kPtr += 262144;   // 256 tokens * 1024 elems
        vPtr += 64;       // 64 keys along i-dim
    };

    auto compute = [&](int buf) {
        // S^T[key][q] = K·Q^T : A=K (4 key-tiles), B=Q (2 q-tiles, regs)
        floatx4 sacc[4][2];
#pragma unroll
        for (int k4 = 0; k4 < 4; k4++)
#pragma unroll
            for (int rt = 0; rt < 2; rt++) sacc[k4][rt] = (floatx4){0.f, 0.f, 0.f, 0.f};
        __builtin_amdgcn_s_setprio(1);
#pragma unroll
        for (int ks = 0; ks < 2; ks++) {
            short8 kf[4];
#pragma unroll
            for (int k4 = 0; k4 < 4; k4++)
                kf[k4] = *(const short8*)(&Ks[buf][(((k4 * 2 + ks) * 4 + g) * 16 + c) * 8]);
#pragma unroll
            for (int k4 = 0; k4 < 4; k4++)
#pragma unroll
                for (int rt = 0; rt < 2; rt++)
                    sacc[k4][rt] = __builtin_amdgcn_mfma_f32_16x16x32_bf16(kf[k4], qf[rt][ks], sacc[k4][rt], 0, 0, 0);
        }
        __builtin_amdgcn_s_setprio(0);

        // p = exp2(s), pack pairs via v_perm_b32, write b64 to per-wave Ps
#pragma unroll
        for (int k4 = 0; k4 < 4; k4++) {
            const int kc = k4 >> 1;
            const int gr = (k4 & 1) * 2 + (g >> 1);
            const int j0 = (g & 1) * 4;
#pragma unroll
            for (int rt = 0; rt < 2; rt++) {
                unsigned int u0 = fbits(__builtin_amdgcn_exp2f(sacc[k4][rt][0])) + 0x8000u;
                unsigned int u1 = fbits(__builtin_amdgcn_exp2f(sacc[k4][rt][1])) + 0x8000u;
                unsigned int u2 = fbits(__builtin_amdgcn_exp2f(sacc[k4][rt][2])) + 0x8000u;
                unsigned int u3 = fbits(__builtin_amdgcn_exp2f(sacc[k4][rt][3])) + 0x8000u;
                uint2 pk;
                pk.x = __builtin_amdgcn_perm(u1, u0, 0x07060302u);  // [e1.hi16 : e0.hi16]
                pk.y = __builtin_amdgcn_perm(u3, u2, 0x07060302u);
                *(uint2*)(Ps + w * 2048 + (((rt * 2 + kc) * 4 + gr) * 16 + c) * 8 + j0) = pk;
            }
        }

        // O += P·V ; l += P·1  (ones B-frag -> l lands oacc-aligned per row)
        __builtin_amdgcn_s_setprio(1);
#pragma unroll
        for (int kc = 0; kc < 2; kc++) {
            short8 pf[2], vf[4];
#pragma unroll
            for (int rt = 0; rt < 2; rt++)
                pf[rt] = *(const short8*)(Ps + w * 2048 + (((rt * 2 + kc) * 4 + g) * 16 + c) * 8);
#pragma unroll
            for (int dt = 0; dt < 4; dt++)
                vf[dt] = *(const short8*)(&Vs[buf][(((dt * 2 + kc) * 4 + g) * 16 + c) * 8]);
#pragma unroll
            for (int rt = 0; rt < 2; rt++) {
                lacc[rt] = __builtin_amdgcn_mfma_f32_16x16x32_bf16(pf[rt], ones, lacc[rt], 0, 0, 0);
#pragma unroll
                for (int dt = 0; dt < 4; dt++)
                    oacc[rt][dt] = __builtin_amdgcn_mfma_f32_16x16x32_bf16(pf[rt], vf[dt], oacc[rt][dt], 0, 0, 0);
            }
        }
        __builtin_amdgcn_s_setprio(0);
    };

    // prologue: stage kt=0 into buf 0
    stage(0);
    __syncthreads();

    // steady: prefetch kt+1 into buf^1, compute kt from buf, full-drain barrier
    for (int kt = 0; kt < 15; ++kt) {
        const int buf = kt & 1;
        stage(buf ^ 1);
        compute(buf);
        __syncthreads();
    }
    compute(1);   // kt = 15, no further staging

    // epilogue: l is already per-row in matching slots; normalize and scatter
#pragma unroll
    for (int rt = 0; rt < 2; rt++) {
#pragma unroll
        for (int r = 0; r < 4; r++) {
            float inv = 1.0f / lacc[rt][r];
            int token = m + 4 * (qt * 128 + w * 32 + rt * 16 + g * 4 + r);
            size_t rowOff = (rowBase + token) * 1024 + h * 64;
#pragma unroll
            for (int dt = 0; dt < 4; dt++)
                Og[rowOff + dt * 16 + c] = f2b(oacc[rt][dt][r] * inv);
        }
    }
}

extern "C" void kernel_launch(void* const* d_in, const int* in_sizes, int n_in,
                              void* d_out, int out_size, void* d_ws, size_t ws_size,
                              hipStream_t stream) {
    const float* x  = (const float*)d_in[0];
    const float* Wq = (const float*)d_in[1];
    const float* bq = (const float*)d_in[2];
    const float* Wk = (const float*)d_in[3];
    const float* bk = (const float*)d_in[4];
    const float* Wv = (const float*)d_in[5];
    const float* bv = (const float*)d_in[6];
    const float* Wo = (const float*)d_in[7];
    const float* bo = (const float*)d_in[8];

    const float SC = 0.18033688011112042f;  // (1/8) * log2(e), folded into Wq/bq

    char* ws = (char*)d_ws;
    const size_t SZ = 33554432;  // 32 MB = 16M bf16
    unsigned short* xb  = (unsigned short*)(ws);          // dead after QKV gemm
    unsigned short* Vtp = (unsigned short*)(ws);          // reuses xb region
    unsigned short* qb  = (unsigned short*)(ws + SZ);     // q,k,v contiguous
    unsigned short* ob  = (unsigned short*)(ws + 4 * SZ);
    unsigned short* Wt3 = (unsigned short*)(ws + 5 * SZ);
    unsigned short* Wot = Wt3 + 3ull * 1024 * 1024;

    cvt_kernel<<<16384, 256, 0, stream>>>(x, xb, 4194304);
    cvt_w_t<<<dim3(16, 16, 4), 256, 0, stream>>>(Wq, Wk, Wv, Wo, Wt3, Wot, SC);
    gemm_k<false><<<1536, 256, 0, stream>>>(xb, Wt3, bq, bk, bv, qb, SC);
    vtrans<<<dim3(16, 256), 256, 0, stream>>>(qb + 2ull * 16777216ull, Vtp);
    attn_k<<<2048, 256, 0, stream>>>(qb, qb + 16777216ull, Vtp, ob);
    gemm_k<true><<<512, 256, 0, stream>>>(ob, Wot, bo, bo, bo, d_out, 1.0f);
}

// Round 8
// 392.736 us; speedup vs baseline: 1.0884x; 1.0048x over previous
//
#include <hip/hip_runtime.h>
#include <hip/hip_bf16.h>

// B=4, L=4096, D=1024, H=16, M=4, dk=64, n=1024. All-bf16 MFMA pipeline.
// R15: isolate R14's correctness failure. R14 changed BOTH the P bf16-packing
// (perm -> v_cvt_pk_bf16_f32, UNVERIFIED operand semantics) and the Ps buffer
// (kc-split WAR reuse). This round keeps the kc-split (LDS 48->40KB -> 4
// blocks/CU) but REVERTS packing to the proven +0x8000 + v_perm_b32 path.
// Pass => cvt_pk was the bug (parked). Fail => kc-split WAR is real.
// Also keeps: grid-stride cvt_kernel (2048 blocks, 16B stores),
// launch_bounds(256,4) on attn. gemm_k unchanged (proven 116us QKV).

typedef __attribute__((ext_vector_type(8))) short short8;
typedef __attribute__((ext_vector_type(8))) unsigned short ushort8v;
typedef __attribute__((ext_vector_type(4))) float floatx4;

__device__ __forceinline__ float b2f(unsigned short h) {
    union { unsigned int u; float f; } v; v.u = ((unsigned int)h) << 16; return v.f;
}
__device__ __forceinline__ unsigned short f2b(float f) {
    union { float f; unsigned int u; } v; v.f = f;
    unsigned int r = v.u + 0x7fffu + ((v.u >> 16) & 1u);
    return (unsigned short)(r >> 16);
}
__device__ __forceinline__ unsigned int fbits(float f) {
    union { float f; unsigned int u; } v; v.f = f; return v.u;
}
__device__ __forceinline__ void async_copy16(const unsigned short* g, unsigned short* l) {
    __builtin_amdgcn_global_load_lds((const __attribute__((address_space(1))) void*)g,
                                     (__attribute__((address_space(3))) void*)l, 16, 0, 0);
}

// ---------------- fp32 -> bf16 convert (x): grid-stride, 16B stores ----------------
__global__ __launch_bounds__(256)
void cvt_kernel(const float* __restrict__ in, unsigned short* __restrict__ out, int n8) {
    for (int i = blockIdx.x * 256 + threadIdx.x; i < n8; i += 2048 * 256) {
        float4 a = ((const float4*)in)[2 * (size_t)i];
        float4 b = ((const float4*)in)[2 * (size_t)i + 1];
        ushort8v o;
        o[0] = f2b(a.x); o[1] = f2b(a.y); o[2] = f2b(a.z); o[3] = f2b(a.w);
        o[4] = f2b(b.x); o[5] = f2b(b.y); o[6] = f2b(b.z); o[7] = f2b(b.w);
        *(ushort8v*)(out + 8 * (size_t)i) = o;
    }
}

// ---------------- W [K][N] fp32 -> Wt [N][K] bf16, all 4 weights in one grid ----------------
__global__ __launch_bounds__(256)
void cvt_w_t(const float* __restrict__ Wq, const float* __restrict__ Wk,
             const float* __restrict__ Wv, const float* __restrict__ Wo,
             unsigned short* __restrict__ Wt3, unsigned short* __restrict__ Wot, float s0) {
    __shared__ float tile[64][65];
    const int kt = blockIdx.x, nt = blockIdx.y, z = blockIdx.z;
    const float* W = (z == 0) ? Wq : (z == 1) ? Wk : (z == 2) ? Wv : Wo;
    unsigned short* Wt = (z < 3) ? (Wt3 + (size_t)z * 1048576) : Wot;
    const float sc = (z == 0) ? s0 : 1.0f;
    const int t = threadIdx.x;
    const int r = t >> 2, cg = t & 3;
    const float* src = W + (size_t)(kt * 64 + r) * 1024 + nt * 64 + cg * 16;
#pragma unroll
    for (int j = 0; j < 4; j++) {
        float4 v = *(const float4*)(src + j * 4);
        tile[r][cg * 16 + j * 4 + 0] = v.x;
        tile[r][cg * 16 + j * 4 + 1] = v.y;
        tile[r][cg * 16 + j * 4 + 2] = v.z;
        tile[r][cg * 16 + j * 4 + 3] = v.w;
    }
    __syncthreads();
    unsigned short* dst = Wt + (size_t)(nt * 64 + r) * 1024 + kt * 64 + cg * 16;
    ushort8v o0, o1;
#pragma unroll
    for (int j = 0; j < 8; j++) o0[j] = f2b(tile[cg * 16 + j][r] * sc);
#pragma unroll
    for (int j = 0; j < 8; j++) o1[j] = f2b(tile[cg * 16 + 8 + j][r] * sc);
    *(ushort8v*)(dst) = o0;
    *(ushort8v*)(dst + 8) = o1;
}

// ---------------- GEMM: C[M][N] = A[M][K] * Bt[N][K]^T + bias*bs ----------------
// BM=256, BN=128, BK=64; 4 waves (2x2), 8x4 accum/wave = 64 MFMA per K-iter.
// LDS XOR swizzle: chunk(row,kc) @ elem (row*8 + (kc^(row&7)))*8.
// Grid 512*nz: xcd=id&7, q=id>>3, tileM=xcd*8+(q&7), rz=q>>3, tileN=rz&7, z=rz>>3.
template <bool F32OUT>
__global__ __launch_bounds__(256, 2)
void gemm_k(const unsigned short* __restrict__ A,
            const unsigned short* __restrict__ BtBase,
            const float* __restrict__ bias0,
            const float* __restrict__ bias1,
            const float* __restrict__ bias2,
            void* __restrict__ OutBase, float s0) {
    constexpr int K = 1024, N = 1024;
    __shared__ __align__(16) unsigned short As[256 * 64];
    __shared__ __align__(16) unsigned short Bs[128 * 64];
    const int id = blockIdx.x;
    const int xcd = id & 7;
    const int q = id >> 3;
    const int tileM = xcd * 8 + (q & 7);
    const int rz = q >> 3;
    const int tileN = rz & 7;
    const int z = rz >> 3;
    const unsigned short* Bt = BtBase + (size_t)z * (1024 * 1024);
    const float* bias = (z == 0) ? bias0 : (z == 1 ? bias1 : bias2);
    const float bs = (z == 0) ? s0 : 1.0f;
    const int tid = threadIdx.x, w = tid >> 6, lane = tid & 63;
    const int wr = w >> 1, wc = w & 1;
    const int g = lane >> 4, c = lane & 15;
    const int c7 = c & 7;
    const int r8 = lane >> 3, j8 = lane & 7;
    const int kcs = (j8 ^ r8) * 8;   // swizzled k-chunk this lane stages

    floatx4 acc[8][4];
#pragma unroll
    for (int i = 0; i < 8; i++)
#pragma unroll
        for (int jj = 0; jj < 4; jj++) acc[i][jj] = (floatx4){0.f, 0.f, 0.f, 0.f};

    for (int kt = 0; kt < K / 64; ++kt) {
        __syncthreads();
#pragma unroll
        for (int t = 0; t < 8; t++) {          // A: 32 segs of 8 rows
            int seg = w * 8 + t;
            int rowA = tileM * 256 + seg * 8 + r8;
            async_copy16(A + (size_t)rowA * K + kt * 64 + kcs, As + seg * 512);
        }
#pragma unroll
        for (int t = 0; t < 4; t++) {          // B: 16 segs of 8 rows
            int seg = w * 4 + t;
            int rowB = tileN * 128 + seg * 8 + r8;
            async_copy16(Bt + (size_t)rowB * K + kt * 64 + kcs, Bs + seg * 512);
        }
        __syncthreads();
#pragma unroll
        for (int ks = 0; ks < 2; ks++) {
            const int kx = ((ks * 4 + g) ^ c7) * 8;
            short8 bf[4];
#pragma unroll
            for (int ct = 0; ct < 4; ct++)
                bf[ct] = *(const short8*)(Bs + (wc * 64 + ct * 16 + c) * 64 + kx);
#pragma unroll
            for (int rt = 0; rt < 8; rt++) {
                short8 af = *(const short8*)(As + (wr * 128 + rt * 16 + c) * 64 + kx);
#pragma unroll
                for (int ct = 0; ct < 4; ct++)
                    acc[rt][ct] = __builtin_amdgcn_mfma_f32_16x16x32_bf16(af, bf[ct], acc[rt][ct], 0, 0, 0);
            }
        }
    }
#pragma unroll
    for (int ct = 0; ct < 4; ct++) {
        int col = tileN * 128 + wc * 64 + ct * 16 + c;
        float bvv = bias[col] * bs;
#pragma unroll
        for (int rt = 0; rt < 8; rt++) {
            int row0 = tileM * 256 + wr * 128 + rt * 16 + g * 4;
#pragma unroll
            for (int r = 0; r < 4; r++) {
                float v = acc[rt][ct][r] + bvv;
                if (F32OUT) {
                    ((float*)OutBase)[(size_t)(row0 + r) * N + col] = v;
                } else {
                    ((unsigned short*)OutBase)[(size_t)z * (16384ull * 1024ull) +
                                               (size_t)(row0 + r) * N + col] = f2b(v);
                }
            }
        }
    }
}

// ---------------- V transpose: v[B,L,D] -> Vt[slice=(b,h,m)][d=64][i=1024] ----------------
__global__ __launch_bounds__(256)
void vtrans(const unsigned short* __restrict__ V, unsigned short* __restrict__ Vt) {
    __shared__ unsigned short tile[64 * 72];
    const int it = blockIdx.x, s = blockIdx.y;
    const int m = s & 3, h = (s >> 2) & 15, b = s >> 6;
    const int tid = threadIdx.x;
    {
        int il = tid >> 2, cg = tid & 3;
        const unsigned short* gsrc =
            V + ((size_t)b * 4096 + m + 4 * (it * 64 + il)) * 1024 + h * 64 + cg * 16;
        *(ushort8v*)(tile + il * 72 + cg * 16) = *(const ushort8v*)gsrc;
        *(ushort8v*)(tile + il * 72 + cg * 16 + 8) = *(const ushort8v*)(gsrc + 8);
    }
    __syncthreads();
    {
        int dl = tid >> 2, ig = (tid & 3) * 16;
        ushort8v o0, o1;
#pragma unroll
        for (int j = 0; j < 8; j++) o0[j] = tile[(ig + j) * 72 + dl];
#pragma unroll
        for (int j = 0; j < 8; j++) o1[j] = tile[(ig + 8 + j) * 72 + dl];
        unsigned short* dst = Vt + (size_t)s * 65536 + (size_t)dl * 1024 + it * 64 + ig;
        *(ushort8v*)dst = o0;
        *(ushort8v*)(dst + 8) = o1;
    }
}

// ---------------- Attention ----------------
// 1-D grid 2048 blocks; decode xcd=id&7, q=id>>3, s=xcd*32+(q>>3), qt=q&7.
// Q frags in registers. S^T = K·Q^T; p=exp2(s) (scale folded into Wq); P
// packed to bf16 via the PROVEN +0x8000 + v_perm_b32 path into per-wave
// kc-split Ps (2KB/wave, reused across kc halves — same-wave DS ops execute
// in order, WAR safe); O = P·V with all-ones B-frag MFMA accumulating l.
// K/V double-buffered: prefetch kt+1 into buf^1 before computing kt; ONE
// __syncthreads per tile. LDS 40KB -> 4 blocks/CU (launch_bounds(256,4)).
__global__ __launch_bounds__(256, 4)
void attn_k(const unsigned short* __restrict__ Qg,
            const unsigned short* __restrict__ Kg,
            const unsigned short* __restrict__ Vt,
            unsigned short* __restrict__ Og) {
    __shared__ __align__(16) unsigned short Ks[2][64 * 64];  // [buf][kt4][ks][g][c][8]
    __shared__ __align__(16) unsigned short Vs[2][64 * 64];  // [buf][dt][kc][g][c][8]
    __shared__ __align__(16) unsigned short Ps[4 * 1024];    // per-wave [rt*4+gr][c][8] (one kc half)

    const int id = blockIdx.x;
    const int xcd = id & 7;
    const int qq = id >> 3;
    const int s = xcd * 32 + (qq >> 3);
    const int qt = qq & 7;
    const int m = s & 3, h = (s >> 2) & 15, b = s >> 6;
    const int tid = threadIdx.x, w = tid >> 6, lane = tid & 63;
    const int g = lane >> 4, c = lane & 15;
    const size_t rowBase = (size_t)b * 4096;

    // Q fragments straight to registers (read-once data; 16B/lane)
    short8 qf[2][2];
#pragma unroll
    for (int rt = 0; rt < 2; rt++)
#pragma unroll
        for (int ks = 0; ks < 2; ks++)
            qf[rt][ks] = *(const short8*)(Qg +
                (rowBase + (size_t)(m + 4 * (qt * 128 + w * 32 + rt * 16 + c))) * 1024 +
                h * 64 + ks * 32 + g * 8);

    // strength-reduced staging pointers
    const unsigned short* kPtr =
        Kg + (rowBase + (size_t)(m + 4 * (w * 16 + c))) * 1024 + h * 64 + g * 8;
    const unsigned short* vPtr =
        Vt + (size_t)s * 65536 + (size_t)(w * 16 + c) * 1024 + g * 8;

    // all-ones B-fragment: l-column trick
    short8 ones;
#pragma unroll
    for (int j = 0; j < 8; j++) ones[j] = (short)0x3F80;   // bf16 1.0

    floatx4 oacc[2][4], lacc[2];
#pragma unroll
    for (int rt = 0; rt < 2; rt++) {
        lacc[rt] = (floatx4){0.f, 0.f, 0.f, 0.f};
#pragma unroll
        for (int dt = 0; dt < 4; dt++) oacc[rt][dt] = (floatx4){0.f, 0.f, 0.f, 0.f};
    }

    unsigned short* Pw = Ps + w * 1024;   // per-wave 2KB half-buffer

    auto stage = [&](int nb) {
        async_copy16(kPtr,      &Ks[nb][(w * 2 + 0) * 512]);
        async_copy16(kPtr + 32, &Ks[nb][(w * 2 + 1) * 512]);
        async_copy16(vPtr,      &Vs[nb][(w * 2 + 0) * 512]);
        async_copy16(vPtr + 32, &Vs[nb][(w * 2 + 1) * 512]);
        kPtr += 262144;   // 256 tokens * 1024 elems
        vPtr += 64;       // 64 keys along i-dim
    };

    auto compute = [&](int buf) {
        // S^T[key][q] = K·Q^T : A=K (4 key-tiles), B=Q (2 q-tiles, regs)
        floatx4 sacc[4][2];
#pragma unroll
        for (int k4 = 0; k4 < 4; k4++)
#pragma unroll
            for (int rt = 0; rt < 2; rt++) sacc[k4][rt] = (floatx4){0.f, 0.f, 0.f, 0.f};
        __builtin_amdgcn_s_setprio(1);
#pragma unroll
        for (int ks = 0; ks < 2; ks++) {
            short8 kf[4];
#pragma unroll
            for (int k4 = 0; k4 < 4; k4++)
                kf[k4] = *(const short8*)(&Ks[buf][(((k4 * 2 + ks) * 4 + g) * 16 + c) * 8]);
#pragma unroll
            for (int k4 = 0; k4 < 4; k4++)
#pragma unroll
                for (int rt = 0; rt < 2; rt++)
                    sacc[k4][rt] = __builtin_amdgcn_mfma_f32_16x16x32_bf16(kf[k4], qf[rt][ks], sacc[k4][rt], 0, 0, 0);
        }
        __builtin_amdgcn_s_setprio(0);

        // per kc half: p = exp2(s) -> +0x8000 + v_perm_b32 pack -> Pw -> PV
#pragma unroll
        for (int kc = 0; kc < 2; kc++) {
#pragma unroll
            for (int kh = 0; kh < 2; kh++) {
                const int k4 = kc * 2 + kh;
                const int gr = kh * 2 + (g >> 1);
                const int j0 = (g & 1) * 4;
#pragma unroll
                for (int rt = 0; rt < 2; rt++) {
                    unsigned int u0 = fbits(__builtin_amdgcn_exp2f(sacc[k4][rt][0])) + 0x8000u;
                    unsigned int u1 = fbits(__builtin_amdgcn_exp2f(sacc[k4][rt][1])) + 0x8000u;
                    unsigned int u2 = fbits(__builtin_amdgcn_exp2f(sacc[k4][rt][2])) + 0x8000u;
                    unsigned int u3 = fbits(__builtin_amdgcn_exp2f(sacc[k4][rt][3])) + 0x8000u;
                    uint2 pk;
                    pk.x = __builtin_amdgcn_perm(u1, u0, 0x07060302u);  // [e1.hi16 : e0.hi16]
                    pk.y = __builtin_amdgcn_perm(u3, u2, 0x07060302u);
                    *(uint2*)(Pw + ((rt * 4 + gr) * 16 + c) * 8 + j0) = pk;
                }
            }
            // O += P·V ; l += P·1  (ones B-frag -> l lands oacc-aligned per row)
            short8 pf[2], vf[4];
#pragma unroll
            for (int rt = 0; rt < 2; rt++)
                pf[rt] = *(const short8*)(Pw + ((rt * 4 + g) * 16 + c) * 8);
#pragma unroll
            for (int dt = 0; dt < 4; dt++)
                vf[dt] = *(const short8*)(&Vs[buf][(((dt * 2 + kc) * 4 + g) * 16 + c) * 8]);
            __builtin_amdgcn_s_setprio(1);
#pragma unroll
            for (int rt = 0; rt < 2; rt++) {
                lacc[rt] = __builtin_amdgcn_mfma_f32_16x16x32_bf16(pf[rt], ones, lacc[rt], 0, 0, 0);
#pragma unroll
                for (int dt = 0; dt < 4; dt++)
                    oacc[rt][dt] = __builtin_amdgcn_mfma_f32_16x16x32_bf16(pf[rt], vf[dt], oacc[rt][dt], 0, 0, 0);
            }
            __builtin_amdgcn_s_setprio(0);
        }
    };

    // prologue: stage kt=0 into buf 0
    stage(0);
    __syncthreads();

    // steady: prefetch kt+1 into buf^1, compute kt from buf, full-drain barrier
    for (int kt = 0; kt < 15; ++kt) {
        const int buf = kt & 1;
        stage(buf ^ 1);
        compute(buf);
        __syncthreads();
    }
    compute(1);   // kt = 15, no further staging

    // epilogue: l is already per-row in matching slots; normalize and scatter
#pragma unroll
    for (int rt = 0; rt < 2; rt++) {
#pragma unroll
        for (int r = 0; r < 4; r++) {
            float inv = 1.0f / lacc[rt][r];
            int token = m + 4 * (qt * 128 + w * 32 + rt * 16 + g * 4 + r);
            size_t rowOff = (rowBase + token) * 1024 + h * 64;
#pragma unroll
            for (int dt = 0; dt < 4; dt++)
                Og[rowOff + dt * 16 + c] = f2b(oacc[rt][dt][r] * inv);
        }
    }
}

extern "C" void kernel_launch(void* const* d_in, const int* in_sizes, int n_in,
                              void* d_out, int out_size, void* d_ws, size_t ws_size,
                              hipStream_t stream) {
    const float* x  = (const float*)d_in[0];
    const float* Wq = (const float*)d_in[1];
    const float* bq = (const float*)d_in[2];
    const float* Wk = (const float*)d_in[3];
    const float* bk = (const float*)d_in[4];
    const float* Wv = (const float*)d_in[5];
    const float* bv = (const float*)d_in[6];
    const float* Wo = (const float*)d_in[7];
    const float* bo = (const float*)d_in[8];

    const float SC = 0.18033688011112042f;  // (1/8) * log2(e), folded into Wq/bq

    char* ws = (char*)d_ws;
    const size_t SZ = 33554432;  // 32 MB = 16M bf16
    unsigned short* xb  = (unsigned short*)(ws);          // dead after QKV gemm
    unsigned short* Vtp = (unsigned short*)(ws);          // reuses xb region
    unsigned short* qb  = (unsigned short*)(ws + SZ);     // q,k,v contiguous
    unsigned short* ob  = (unsigned short*)(ws + 4 * SZ);
    unsigned short* Wt3 = (unsigned short*)(ws + 5 * SZ);
    unsigned short* Wot = Wt3 + 3ull * 1024 * 1024;

    cvt_kernel<<<2048, 256, 0, stream>>>(x, xb, 2097152);
    cvt_w_t<<<dim3(16, 16, 4), 256, 0, stream>>>(Wq, Wk, Wv, Wo, Wt3, Wot, SC);
    gemm_k<false><<<1536, 256, 0, stream>>>(xb, Wt3, bq, bk, bv, qb, SC);
    vtrans<<<dim3(16, 256), 256, 0, stream>>>(qb + 2ull * 16777216ull, Vtp);
    attn_k<<<2048, 256, 0, stream>>>(qb, qb + 16777216ull, Vtp, ob);
    gemm_k<true><<<512, 256, 0, stream>>>(ob, Wot, bo, bo, bo, d_out, 1.0f);
}

// Round 9
// 385.436 us; speedup vs baseline: 1.1091x; 1.0189x over previous
//
#include <hip/hip_runtime.h>
#include <hip/hip_bf16.h>

// B=4, L=4096, D=1024, H=16, M=4, dk=64, n=1024. All-bf16 MFMA pipeline.
// R16: attn K/V-reuse doubling. R15 analysis: each 256KB K/V slice is read by
// 8 qt-blocks -> 512MB grid-total K/V traffic, per-XCD working set = 4MB =
// exactly L2 -> thrash to HBM. Fix: 512-thread attn blocks (8 waves), each
// covering 256 q-rows (qt 8->4, grid 1024): K/V staged once per 8 waves ->
// traffic halves to 256MB; per-wave staging instrs halve. Per-wave compute,
// register budget, and all LDS layouts byte-identical to R15 (only seg->wave
// assignment + q-row base changed). launch_bounds(512,4): VGPR cap 128,
// 2 blocks/CU = same 16 waves/CU as R15. LDS 48KB/block.
// gemm_k / cvt / cvt_w_t / vtrans unchanged from R15 (passed, 392.7us).

typedef __attribute__((ext_vector_type(8))) short short8;
typedef __attribute__((ext_vector_type(8))) unsigned short ushort8v;
typedef __attribute__((ext_vector_type(4))) float floatx4;

__device__ __forceinline__ float b2f(unsigned short h) {
    union { unsigned int u; float f; } v; v.u = ((unsigned int)h) << 16; return v.f;
}
__device__ __forceinline__ unsigned short f2b(float f) {
    union { float f; unsigned int u; } v; v.f = f;
    unsigned int r = v.u + 0x7fffu + ((v.u >> 16) & 1u);
    return (unsigned short)(r >> 16);
}
__device__ __forceinline__ unsigned int fbits(float f) {
    union { float f; unsigned int u; } v; v.f = f; return v.u;
}
__device__ __forceinline__ void async_copy16(const unsigned short* g, unsigned short* l) {
    __builtin_amdgcn_global_load_lds((const __attribute__((address_space(1))) void*)g,
                                     (__attribute__((address_space(3))) void*)l, 16, 0, 0);
}

// ---------------- fp32 -> bf16 convert (x): grid-stride, 16B stores ----------------
__global__ __launch_bounds__(256)
void cvt_kernel(const float* __restrict__ in, unsigned short* __restrict__ out, int n8) {
    for (int i = blockIdx.x * 256 + threadIdx.x; i < n8; i += 2048 * 256) {
        float4 a = ((const float4*)in)[2 * (size_t)i];
        float4 b = ((const float4*)in)[2 * (size_t)i + 1];
        ushort8v o;
        o[0] = f2b(a.x); o[1] = f2b(a.y); o[2] = f2b(a.z); o[3] = f2b(a.w);
        o[4] = f2b(b.x); o[5] = f2b(b.y); o[6] = f2b(b.z); o[7] = f2b(b.w);
        *(ushort8v*)(out + 8 * (size_t)i) = o;
    }
}

// ---------------- W [K][N] fp32 -> Wt [N][K] bf16, all 4 weights in one grid ----------------
__global__ __launch_bounds__(256)
void cvt_w_t(const float* __restrict__ Wq, const float* __restrict__ Wk,
             const float* __restrict__ Wv, const float* __restrict__ Wo,
             unsigned short* __restrict__ Wt3, unsigned short* __restrict__ Wot, float s0) {
    __shared__ float tile[64][65];
    const int kt = blockIdx.x, nt = blockIdx.y, z = blockIdx.z;
    const float* W = (z == 0) ? Wq : (z == 1) ? Wk : (z == 2) ? Wv : Wo;
    unsigned short* Wt = (z < 3) ? (Wt3 + (size_t)z * 1048576) : Wot;
    const float sc = (z == 0) ? s0 : 1.0f;
    const int t = threadIdx.x;
    const int r = t >> 2, cg = t & 3;
    const float* src = W + (size_t)(kt * 64 + r) * 1024 + nt * 64 + cg * 16;
#pragma unroll
    for (int j = 0; j < 4; j++) {
        float4 v = *(const float4*)(src + j * 4);
        tile[r][cg * 16 + j * 4 + 0] = v.x;
        tile[r][cg * 16 + j * 4 + 1] = v.y;
        tile[r][cg * 16 + j * 4 + 2] = v.z;
        tile[r][cg * 16 + j * 4 + 3] = v.w;
    }
    __syncthreads();
    unsigned short* dst = Wt + (size_t)(nt * 64 + r) * 1024 + kt * 64 + cg * 16;
    ushort8v o0, o1;
#pragma unroll
    for (int j = 0; j < 8; j++) o0[j] = f2b(tile[cg * 16 + j][r] * sc);
#pragma unroll
    for (int j = 0; j < 8; j++) o1[j] = f2b(tile[cg * 16 + 8 + j][r] * sc);
    *(ushort8v*)(dst) = o0;
    *(ushort8v*)(dst + 8) = o1;
}

// ---------------- GEMM: C[M][N] = A[M][K] * Bt[N][K]^T + bias*bs ----------------
// BM=256, BN=128, BK=64; 4 waves (2x2), 8x4 accum/wave = 64 MFMA per K-iter.
// LDS XOR swizzle: chunk(row,kc) @ elem (row*8 + (kc^(row&7)))*8.
// Grid 512*nz: xcd=id&7, q=id>>3, tileM=xcd*8+(q&7), rz=q>>3, tileN=rz&7, z=rz>>3.
template <bool F32OUT>
__global__ __launch_bounds__(256, 2)
void gemm_k(const unsigned short* __restrict__ A,
            const unsigned short* __restrict__ BtBase,
            const float* __restrict__ bias0,
            const float* __restrict__ bias1,
            const float* __restrict__ bias2,
            void* __restrict__ OutBase, float s0) {
    constexpr int K = 1024, N = 1024;
    __shared__ __align__(16) unsigned short As[256 * 64];
    __shared__ __align__(16) unsigned short Bs[128 * 64];
    const int id = blockIdx.x;
    const int xcd = id & 7;
    const int q = id >> 3;
    const int tileM = xcd * 8 + (q & 7);
    const int rz = q >> 3;
    const int tileN = rz & 7;
    const int z = rz >> 3;
    const unsigned short* Bt = BtBase + (size_t)z * (1024 * 1024);
    const float* bias = (z == 0) ? bias0 : (z == 1 ? bias1 : bias2);
    const float bs = (z == 0) ? s0 : 1.0f;
    const int tid = threadIdx.x, w = tid >> 6, lane = tid & 63;
    const int wr = w >> 1, wc = w & 1;
    const int g = lane >> 4, c = lane & 15;
    const int c7 = c & 7;
    const int r8 = lane >> 3, j8 = lane & 7;
    const int kcs = (j8 ^ r8) * 8;   // swizzled k-chunk this lane stages

    floatx4 acc[8][4];
#pragma unroll
    for (int i = 0; i < 8; i++)
#pragma unroll
        for (int jj = 0; jj < 4; jj++) acc[i][jj] = (floatx4){0.f, 0.f, 0.f, 0.f};

    for (int kt = 0; kt < K / 64; ++kt) {
        __syncthreads();
#pragma unroll
        for (int t = 0; t < 8; t++) {          // A: 32 segs of 8 rows
            int seg = w * 8 + t;
            int rowA = tileM * 256 + seg * 8 + r8;
            async_copy16(A + (size_t)rowA * K + kt * 64 + kcs, As + seg * 512);
        }
#pragma unroll
        for (int t = 0; t < 4; t++) {          // B: 16 segs of 8 rows
            int seg = w * 4 + t;
            int rowB = tileN * 128 + seg * 8 + r8;
            async_copy16(Bt + (size_t)rowB * K + kt * 64 + kcs, Bs + seg * 512);
        }
        __syncthreads();
#pragma unroll
        for (int ks = 0; ks < 2; ks++) {
            const int kx = ((ks * 4 + g) ^ c7) * 8;
            short8 bf[4];
#pragma unroll
            for (int ct = 0; ct < 4; ct++)
                bf[ct] = *(const short8*)(Bs + (wc * 64 + ct * 16 + c) * 64 + kx);
#pragma unroll
            for (int rt = 0; rt < 8; rt++) {
                short8 af = *(const short8*)(As + (wr * 128 + rt * 16 + c) * 64 + kx);
#pragma unroll
                for (int ct = 0; ct < 4; ct++)
                    acc[rt][ct] = __builtin_amdgcn_mfma_f32_16x16x32_bf16(af, bf[ct], acc[rt][ct], 0, 0, 0);
            }
        }
    }
#pragma unroll
    for (int ct = 0; ct < 4; ct++) {
        int col = tileN * 128 + wc * 64 + ct * 16 + c;
        float bvv = bias[col] * bs;
#pragma unroll
        for (int rt = 0; rt < 8; rt++) {
            int row0 = tileM * 256 + wr * 128 + rt * 16 + g * 4;
#pragma unroll
            for (int r = 0; r < 4; r++) {
                float v = acc[rt][ct][r] + bvv;
                if (F32OUT) {
                    ((float*)OutBase)[(size_t)(row0 + r) * N + col] = v;
                } else {
                    ((unsigned short*)OutBase)[(size_t)z * (16384ull * 1024ull) +
                                               (size_t)(row0 + r) * N + col] = f2b(v);
                }
            }
        }
    }
}

// ---------------- V transpose: v[B,L,D] -> Vt[slice=(b,h,m)][d=64][i=1024] ----------------
__global__ __launch_bounds__(256)
void vtrans(const unsigned short* __restrict__ V, unsigned short* __restrict__ Vt) {
    __shared__ unsigned short tile[64 * 72];
    const int it = blockIdx.x, s = blockIdx.y;
    const int m = s & 3, h = (s >> 2) & 15, b = s >> 6;
    const int tid = threadIdx.x;
    {
        int il = tid >> 2, cg = tid & 3;
        const unsigned short* gsrc =
            V + ((size_t)b * 4096 + m + 4 * (it * 64 + il)) * 1024 + h * 64 + cg * 16;
        *(ushort8v*)(tile + il * 72 + cg * 16) = *(const ushort8v*)gsrc;
        *(ushort8v*)(tile + il * 72 + cg * 16 + 8) = *(const ushort8v*)(gsrc + 8);
    }
    __syncthreads();
    {
        int dl = tid >> 2, ig = (tid & 3) * 16;
        ushort8v o0, o1;
#pragma unroll
        for (int j = 0; j < 8; j++) o0[j] = tile[(ig + j) * 72 + dl];
#pragma unroll
        for (int j = 0; j < 8; j++) o1[j] = tile[(ig + 8 + j) * 72 + dl];
        unsigned short* dst = Vt + (size_t)s * 65536 + (size_t)dl * 1024 + it * 64 + ig;
        *(ushort8v*)dst = o0;
        *(ushort8v*)(dst + 8) = o1;
    }
}

// ---------------- Attention ----------------
// Grid 1024 blocks x 512 thr (8 waves); decode xcd=id&7, qq=id>>3,
// s=xcd*32+(qq>>2), qt=qq&3. Each block: 256 q-rows of one slice; wave w owns
// rows [w*32, w*32+32). K/V tile staged ONCE per block (8 waves share):
// wave w stages seg w of Ks and Vs (1 copy each; seg = (w>>1)*2+(w&1) keeps
// R15's proven layout). Per-wave compute identical to R15: S^T = K.Q^T,
// p=exp2(s), +0x8000+v_perm pack into per-wave kc-split Ps (2KB/wave), PV via
// MFMA with all-ones l-column. Double-buffered K/V, one __syncthreads/tile.
__global__ __launch_bounds__(512, 4)
void attn_k(const unsigned short* __restrict__ Qg,
            const unsigned short* __restrict__ Kg,
            const unsigned short* __restrict__ Vt,
            unsigned short* __restrict__ Og) {
    __shared__ __align__(16) unsigned short Ks[2][64 * 64];  // [buf][seg=8][lane*8]
    __shared__ __align__(16) unsigned short Vs[2][64 * 64];  // [buf][seg=8][lane*8]
    __shared__ __align__(16) unsigned short Ps[8 * 1024];    // per-wave [rt*4+gr][c][8] (one kc half)

    const int id = blockIdx.x;
    const int xcd = id & 7;
    const int qq = id >> 3;
    const int s = xcd * 32 + (qq >> 2);
    const int qt = qq & 3;
    const int m = s & 3, h = (s >> 2) & 15, b = s >> 6;
    const int tid = threadIdx.x, w = tid >> 6, lane = tid & 63;
    const int g = lane >> 4, c = lane & 15;
    const size_t rowBase = (size_t)b * 4096;

    // Q fragments straight to registers (read-once data; 16B/lane)
    short8 qf[2][2];
#pragma unroll
    for (int rt = 0; rt < 2; rt++)
#pragma unroll
        for (int ks = 0; ks < 2; ks++)
            qf[rt][ks] = *(const short8*)(Qg +
                (rowBase + (size_t)(m + 4 * (qt * 256 + w * 32 + rt * 16 + c))) * 1024 +
                h * 64 + ks * 32 + g * 8);

    // staging pointers: wave w stages seg w (token-halves w>>1, dim-half w&1)
    const unsigned short* kPtr =
        Kg + (rowBase + (size_t)(m + 4 * ((w >> 1) * 16 + c))) * 1024 + h * 64 + (w & 1) * 32 + g * 8;
    const unsigned short* vPtr =
        Vt + (size_t)s * 65536 + (size_t)((w >> 1) * 16 + c) * 1024 + (w & 1) * 32 + g * 8;

    // all-ones B-fragment: l-column trick
    short8 ones;
#pragma unroll
    for (int j = 0; j < 8; j++) ones[j] = (short)0x3F80;   // bf16 1.0

    floatx4 oacc[2][4], lacc[2];
#pragma unroll
    for (int rt = 0; rt < 2; rt++) {
        lacc[rt] = (floatx4){0.f, 0.f, 0.f, 0.f};
#pragma unroll
        for (int dt = 0; dt < 4; dt++) oacc[rt][dt] = (floatx4){0.f, 0.f, 0.f, 0.f};
    }

    unsigned short* Pw = Ps + w * 1024;   // per-wave 2KB half-buffer

    auto stage = [&](int nb) {
        async_copy16(kPtr, &Ks[nb][w * 512]);
        async_copy16(vPtr, &Vs[nb][w * 512]);
        kPtr += 262144;   // 256 tokens * 1024 elems
        vPtr += 64;       // 64 keys along i-dim
    };

    auto compute = [&](int buf) {
        // S^T[key][q] = K·Q^T : A=K (4 key-tiles), B=Q (2 q-tiles, regs)
        floatx4 sacc[4][2];
#pragma unroll
        for (int k4 = 0; k4 < 4; k4++)
#pragma unroll
            for (int rt = 0; rt < 2; rt++) sacc[k4][rt] = (floatx4){0.f, 0.f, 0.f, 0.f};
        __builtin_amdgcn_s_setprio(1);
#pragma unroll
        for (int ks = 0; ks < 2; ks++) {
            short8 kf[4];
#pragma unroll
            for (int k4 = 0; k4 < 4; k4++)
                kf[k4] = *(const short8*)(&Ks[buf][(((k4 * 2 + ks) * 4 + g) * 16 + c) * 8]);
#pragma unroll
            for (int k4 = 0; k4 < 4; k4++)
#pragma unroll
                for (int rt = 0; rt < 2; rt++)
                    sacc[k4][rt] = __builtin_amdgcn_mfma_f32_16x16x32_bf16(kf[k4], qf[rt][ks], sacc[k4][rt], 0, 0, 0);
        }
        __builtin_amdgcn_s_setprio(0);

        // per kc half: p = exp2(s) -> +0x8000 + v_perm_b32 pack -> Pw -> PV
#pragma unroll
        for (int kc = 0; kc < 2; kc++) {
#pragma unroll
            for (int kh = 0; kh < 2; kh++) {
                const int k4 = kc * 2 + kh;
                const int gr = kh * 2 + (g >> 1);
                const int j0 = (g & 1) * 4;
#pragma unroll
                for (int rt = 0; rt < 2; rt++) {
                    unsigned int u0 = fbits(__builtin_amdgcn_exp2f(sacc[k4][rt][0])) + 0x8000u;
                    unsigned int u1 = fbits(__builtin_amdgcn_exp2f(sacc[k4][rt][1])) + 0x8000u;
                    unsigned int u2 = fbits(__builtin_amdgcn_exp2f(sacc[k4][rt][2])) + 0x8000u;
                    unsigned int u3 = fbits(__builtin_amdgcn_exp2f(sacc[k4][rt][3])) + 0x8000u;
                    uint2 pk;
                    pk.x = __builtin_amdgcn_perm(u1, u0, 0x07060302u);  // [e1.hi16 : e0.hi16]
                    pk.y = __builtin_amdgcn_perm(u3, u2, 0x07060302u);
                    *(uint2*)(Pw + ((rt * 4 + gr) * 16 + c) * 8 + j0) = pk;
                }
            }
            // O += P·V ; l += P·1  (ones B-frag -> l lands oacc-aligned per row)
            short8 pf[2], vf[4];
#pragma unroll
            for (int rt = 0; rt < 2; rt++)
                pf[rt] = *(const short8*)(Pw + ((rt * 4 + g) * 16 + c) * 8);
#pragma unroll
            for (int dt = 0; dt < 4; dt++)
                vf[dt] = *(const short8*)(&Vs[buf][(((dt * 2 + kc) * 4 + g) * 16 + c) * 8]);
            __builtin_amdgcn_s_setprio(1);
#pragma unroll
            for (int rt = 0; rt < 2; rt++) {
                lacc[rt] = __builtin_amdgcn_mfma_f32_16x16x32_bf16(pf[rt], ones, lacc[rt], 0, 0, 0);
#pragma unroll
                for (int dt = 0; dt < 4; dt++)
                    oacc[rt][dt] = __builtin_amdgcn_mfma_f32_16x16x32_bf16(pf[rt], vf[dt], oacc[rt][dt], 0, 0, 0);
            }
            __builtin_amdgcn_s_setprio(0);
        }
    };

    // prologue: stage kt=0 into buf 0
    stage(0);
    __syncthreads();

    // steady: prefetch kt+1 into buf^1, compute kt from buf, full-drain barrier
    for (int kt = 0; kt < 15; ++kt) {
        const int buf = kt & 1;
        stage(buf ^ 1);
        compute(buf);
        __syncthreads();
    }
    compute(1);   // kt = 15, no further staging

    // epilogue: l is already per-row in matching slots; normalize and scatter
#pragma unroll
    for (int rt = 0; rt < 2; rt++) {
#pragma unroll
        for (int r = 0; r < 4; r++) {
            float inv = 1.0f / lacc[rt][r];
            int token = m + 4 * (qt * 256 + w * 32 + rt * 16 + g * 4 + r);
            size_t rowOff = (rowBase + token) * 1024 + h * 64;
#pragma unroll
            for (int dt = 0; dt < 4; dt++)
                Og[rowOff + dt * 16 + c] = f2b(oacc[rt][dt][r] * inv);
        }
    }
}

extern "C" void kernel_launch(void* const* d_in, const int* in_sizes, int n_in,
                              void* d_out, int out_size, void* d_ws, size_t ws_size,
                              hipStream_t stream) {
    const float* x  = (const float*)d_in[0];
    const float* Wq = (const float*)d_in[1];
    const float* bq = (const float*)d_in[2];
    const float* Wk = (const float*)d_in[3];
    const float* bk = (const float*)d_in[4];
    const float* Wv = (const float*)d_in[5];
    const float* bv = (const float*)d_in[6];
    const float* Wo = (const float*)d_in[7];
    const float* bo = (const float*)d_in[8];

    const float SC = 0.18033688011112042f;  // (1/8) * log2(e), folded into Wq/bq

    char* ws = (char*)d_ws;
    const size_t SZ = 33554432;  // 32 MB = 16M bf16
    unsigned short* xb  = (unsigned short*)(ws);          // dead after QKV gemm
    unsigned short* Vtp = (unsigned short*)(ws);          // reuses xb region
    unsigned short* qb  = (unsigned short*)(ws + SZ);     // q,k,v contiguous
    unsigned short* ob  = (unsigned short*)(ws + 4 * SZ);
    unsigned short* Wt3 = (unsigned short*)(ws + 5 * SZ);
    unsigned short* Wot = Wt3 + 3ull * 1024 * 1024;

    cvt_kernel<<<2048, 256, 0, stream>>>(x, xb, 2097152);
    cvt_w_t<<<dim3(16, 16, 4), 256, 0, stream>>>(Wq, Wk, Wv, Wo, Wt3, Wot, SC);
    gemm_k<false><<<1536, 256, 0, stream>>>(xb, Wt3, bq, bk, bv, qb, SC);
    vtrans<<<dim3(16, 256), 256, 0, stream>>>(qb + 2ull * 16777216ull, Vtp);
    attn_k<<<1024, 512, 0, stream>>>(qb, qb + 16777216ull, Vtp, ob);
    gemm_k<true><<<512, 256, 0, stream>>>(ob, Wot, bo, bo, bo, d_out, 1.0f);
}